// Round 1
// baseline (195.462 us; speedup 1.0000x reference)
//
#include <hip/hip_runtime.h>

#define THREADS 256

// B=64, P=50000, H=W=512
__global__ __launch_bounds__(THREADS) void rdc_kernel(
    const float* __restrict__ x,
    const int*   __restrict__ xA,
    const int*   __restrict__ yA,
    const int*   __restrict__ xB,
    const int*   __restrict__ yB,
    const float* __restrict__ gt,
    float* __restrict__ out,
    int nvec, float inv_n)
{
    const int P4 = 50000 / 4;           // vec4 chunks per batch
    const int HW = 512 * 512;

    float acc = 0.0f;
    const int stride = gridDim.x * blockDim.x;
    for (int v = blockIdx.x * blockDim.x + threadIdx.x; v < nvec; v += stride) {
        const int4  xa = reinterpret_cast<const int4*>(xA)[v];
        const int4  ya = reinterpret_cast<const int4*>(yA)[v];
        const int4  xb = reinterpret_cast<const int4*>(xB)[v];
        const int4  yb = reinterpret_cast<const int4*>(yB)[v];
        const float4 g = reinterpret_cast<const float4*>(gt)[v];

        const int b = v / P4;           // all 4 points share this batch (P%4==0)
        const float* __restrict__ img = x + (size_t)b * HW;

        #pragma unroll
        for (int j = 0; j < 4; ++j) {
            int xai = (j == 0) ? xa.x : (j == 1) ? xa.y : (j == 2) ? xa.z : xa.w;
            int yai = (j == 0) ? ya.x : (j == 1) ? ya.y : (j == 2) ? ya.z : ya.w;
            int xbi = (j == 0) ? xb.x : (j == 1) ? xb.y : (j == 2) ? xb.z : xb.w;
            int ybi = (j == 0) ? yb.x : (j == 1) ? yb.y : (j == 2) ? yb.z : yb.w;
            float gi = (j == 0) ? g.x  : (j == 1) ? g.y  : (j == 2) ? g.z  : g.w;

            float zA = img[(yai << 9) + xai];
            float zB = img[(ybi << 9) + xbi];
            float d  = zA - zB;

            float t  = -gi * d;
            // stable softplus: log1p(exp(t)) = max(t,0) + log1p(exp(-|t|))
            float sp = fmaxf(t, 0.0f) + log1pf(__expf(-fabsf(t)));
            float m  = fabsf(gi);     // 0 or 1
            acc += m * sp + (1.0f - m) * d * d;
        }
    }

    // wave64 reduce
    #pragma unroll
    for (int off = 32; off > 0; off >>= 1)
        acc += __shfl_down(acc, off, 64);

    __shared__ float wsum[THREADS / 64];
    const int lane = threadIdx.x & 63;
    const int wid  = threadIdx.x >> 6;
    if (lane == 0) wsum[wid] = acc;
    __syncthreads();
    if (threadIdx.x == 0) {
        float s = 0.0f;
        #pragma unroll
        for (int i = 0; i < THREADS / 64; ++i) s += wsum[i];
        atomicAdd(out, s * inv_n);
    }
}

extern "C" void kernel_launch(void* const* d_in, const int* in_sizes, int n_in,
                              void* d_out, int out_size, void* d_ws, size_t ws_size,
                              hipStream_t stream) {
    const float* x  = (const float*)d_in[0];
    const int*   xA = (const int*)d_in[1];
    const int*   yA = (const int*)d_in[2];
    const int*   xB = (const int*)d_in[3];
    const int*   yB = (const int*)d_in[4];
    const float* gt = (const float*)d_in[5];
    float* out = (float*)d_out;

    const int n    = in_sizes[1];          // B*P = 3,200,000
    const int nvec = n / 4;                // 800,000
    const float inv_n = 1.0f / (float)n;

    hipMemsetAsync(out, 0, sizeof(float), stream);

    const int blocks = (nvec + THREADS - 1) / THREADS;   // 3125
    rdc_kernel<<<blocks, THREADS, 0, stream>>>(x, xA, yA, xB, yB, gt, out, nvec, inv_n);
}

// Round 2
// 170.020 us; speedup vs baseline: 1.1496x; 1.1496x over previous
//
#include <hip/hip_runtime.h>

#define THREADS 256
#define BLOCKS_PER_XCD 192
#define NXCD 8
#define NBLOCKS (BLOCKS_PER_XCD * NXCD)   // 1536

typedef int   intx4   __attribute__((ext_vector_type(4)));
typedef float floatx4 __attribute__((ext_vector_type(4)));

// B=64, P=50000, H=W=512
__global__ __launch_bounds__(THREADS) void rdc_kernel(
    const float* __restrict__ x,
    const int*   __restrict__ xA,
    const int*   __restrict__ yA,
    const int*   __restrict__ xB,
    const int*   __restrict__ yB,
    const float* __restrict__ gt,
    float* __restrict__ out,
    float inv_n)
{
    const int P4  = 12500;            // vec4 chunks per batch
    const int BPX = 8;                // batches per XCD (64/8)
    const int HW  = 512 * 512;

    // Physical mapping: consecutive block ids round-robin across the 8 XCDs.
    const int xcd = blockIdx.x & 7;
    const int lb  = blockIdx.x >> 3;                    // 0..BLOCKS_PER_XCD-1
    const int tlocal = lb * THREADS + threadIdx.x;      // 0..49151
    const int nthreads_xcd = BLOCKS_PER_XCD * THREADS;  // 49152
    const int total = BPX * P4;                         // 100000 chunks per XCD

    float acc = 0.0f;
    for (int j = tlocal; j < total; j += nthreads_xcd) {
        const int bl = j / P4;                 // local batch 0..7 (magic-mul)
        const int i  = j - bl * P4;
        const int b  = xcd * BPX + bl;         // global batch
        const int v  = b * P4 + i;             // vec4 chunk index

        // Read-once streams: nontemporal so they don't evict image lines in L2.
        const intx4  xa = __builtin_nontemporal_load((const intx4*)xA + v);
        const intx4  ya = __builtin_nontemporal_load((const intx4*)yA + v);
        const intx4  xb = __builtin_nontemporal_load((const intx4*)xB + v);
        const intx4  yb = __builtin_nontemporal_load((const intx4*)yB + v);
        const floatx4 g = __builtin_nontemporal_load((const floatx4*)gt + v);

        const float* __restrict__ img = x + (size_t)b * HW;

        #pragma unroll
        for (int k = 0; k < 4; ++k) {
            float zA = img[(ya[k] << 9) + xa[k]];
            float zB = img[(yb[k] << 9) + xb[k]];
            float d  = zA - zB;
            float gi = g[k];

            float t  = -gi * d;
            // stable softplus: log1p(exp(t)) = max(t,0) + log1p(exp(-|t|))
            float sp = fmaxf(t, 0.0f) + log1pf(__expf(-fabsf(t)));
            float m  = fabsf(gi);     // 0 or 1
            acc += m * sp + (1.0f - m) * d * d;
        }
    }

    // wave64 reduce
    #pragma unroll
    for (int off = 32; off > 0; off >>= 1)
        acc += __shfl_down(acc, off, 64);

    __shared__ float wsum[THREADS / 64];
    const int lane = threadIdx.x & 63;
    const int wid  = threadIdx.x >> 6;
    if (lane == 0) wsum[wid] = acc;
    __syncthreads();
    if (threadIdx.x == 0) {
        float s = 0.0f;
        #pragma unroll
        for (int i2 = 0; i2 < THREADS / 64; ++i2) s += wsum[i2];
        atomicAdd(out, s * inv_n);
    }
}

extern "C" void kernel_launch(void* const* d_in, const int* in_sizes, int n_in,
                              void* d_out, int out_size, void* d_ws, size_t ws_size,
                              hipStream_t stream) {
    const float* x  = (const float*)d_in[0];
    const int*   xA = (const int*)d_in[1];
    const int*   yA = (const int*)d_in[2];
    const int*   xB = (const int*)d_in[3];
    const int*   yB = (const int*)d_in[4];
    const float* gt = (const float*)d_in[5];
    float* out = (float*)d_out;

    const int n = in_sizes[1];             // B*P = 3,200,000
    const float inv_n = 1.0f / (float)n;

    hipMemsetAsync(out, 0, sizeof(float), stream);
    rdc_kernel<<<NBLOCKS, THREADS, 0, stream>>>(x, xA, yA, xB, yB, gt, out, inv_n);
}